// Round 2
// baseline (2674.889 us; speedup 1.0000x reference)
//
#include <hip/hip_runtime.h>

// GATv2 3-layer + mean-pool + linear head, MI355X.
// All float tensors are f32 (reference dtype); ints are int32. Output f32.
// Intermediates in f32 workspace (~56 MB).

#define NN 50000
#define NE 1000000
#define ET (NE + NN)          // edges + self loops
#define HID 64
#define DIN0 128
#define NG 256
#define NEG 0.2f

// float atomic max via int/uint monotonic bit trick (m init to -inf)
__device__ __forceinline__ void atomicMaxF(float* addr, float val) {
    if (val >= 0.f) atomicMax((int*)addr, __float_as_int(val));
    else            atomicMin((unsigned*)addr, (unsigned)__float_as_int(val));
}

// ---- init m/den per layer ----
__global__ void k_init_md(float* __restrict__ m, float* __restrict__ den) {
    int i = blockIdx.x * 256 + threadIdx.x;
    if (i < NN) { m[i] = -INFINITY; den[i] = 0.f; }
}

// ---- init pooled/cnt ----
__global__ void k_init_pool(float* __restrict__ pooled, float* __restrict__ cnt) {
    int i = blockIdx.x * 256 + threadIdx.x;
    if (i < NG * HID) pooled[i] = 0.f;
    if (i < NG) cnt[i] = 0.f;
}

// ---- fused node GEMMs: xl = x@Wl^T, xr = x@Wr^T, acc = x@Rw^T + Rb + b ----
// block = 256 threads = 4 nodes x 64 channels; x rows staged in LDS
template <int DIN, bool RELU>
__global__ void k_gemm(const float* __restrict__ xin, const float* __restrict__ Wl,
                       const float* __restrict__ Wr, const float* __restrict__ Rw,
                       const float* __restrict__ bvec, const float* __restrict__ rb,
                       float* __restrict__ xl, float* __restrict__ xr,
                       float* __restrict__ acc) {
    __shared__ __align__(16) float xs[4][DIN];
    int c = threadIdx.x & 63;
    int j = threadIdx.x >> 6;
    int node0 = blockIdx.x * 4;

    for (int i = threadIdx.x; i < 4 * DIN; i += 256) {
        int nd = i / DIN, k = i - nd * DIN;
        int n = node0 + nd;
        float v = 0.f;
        if (n < NN) {
            v = xin[(size_t)n * DIN + k];
            if (RELU) v = fmaxf(v, 0.f);
        }
        xs[nd][k] = v;
    }
    __syncthreads();

    int n = node0 + j;
    if (n >= NN) return;

    const float4* wl4 = (const float4*)(Wl + (size_t)c * DIN);
    const float4* wr4 = (const float4*)(Wr + (size_t)c * DIN);
    const float4* rw4 = (const float4*)(Rw + (size_t)c * DIN);
    const float4* x4  = (const float4*)xs[j];

    float sl = 0.f, sr = 0.f, sv = 0.f;
#pragma unroll
    for (int k = 0; k < DIN / 4; k++) {
        float4 xv = x4[k];
        float4 a = wl4[k];
        float4 b = wr4[k];
        float4 r = rw4[k];
        sl += xv.x * a.x + xv.y * a.y + xv.z * a.z + xv.w * a.w;
        sr += xv.x * b.x + xv.y * b.y + xv.z * b.z + xv.w * b.w;
        sv += xv.x * r.x + xv.y * r.y + xv.z * r.z + xv.w * r.w;
    }
    size_t o = (size_t)n * HID + c;
    xl[o] = sl;
    xr[o] = sr;
    acc[o] = sv + bvec[c] + rb[c];
}

// ---- pass A: logits[e] = leaky(xl[src]+xr[dst]) . att ; m[dst] = max ----
// wave per edge, lane = channel
__global__ void k_edge_logits(const int* __restrict__ esrc, const int* __restrict__ edst,
                              const float* __restrict__ xl, const float* __restrict__ xr,
                              const float* __restrict__ att,
                              float* __restrict__ logits, float* __restrict__ m) {
    int lane = threadIdx.x & 63;
    int e = blockIdx.x * 4 + (threadIdx.x >> 6);
    if (e >= ET) return;
    int s, d;
    if (e < NE) { s = esrc[e]; d = edst[e]; }
    else        { s = d = e - NE; }
    float v = xl[(size_t)s * HID + lane] + xr[(size_t)d * HID + lane];
    v = (v > 0.f) ? v : NEG * v;
    float t = v * att[lane];
#pragma unroll
    for (int o = 32; o; o >>= 1) t += __shfl_xor(t, o, 64);
    if (lane == 0) {
        logits[e] = t;
        atomicMaxF(&m[d], t);
    }
}

// ---- pass B: ex = exp(logit - m[dst]); den[dst] += ex (in-place into logits) ----
__global__ void k_edge_exp(const int* __restrict__ edst, const float* __restrict__ m,
                           float* __restrict__ logits, float* __restrict__ den) {
    int e = blockIdx.x * 256 + threadIdx.x;
    if (e >= ET) return;
    int d = (e < NE) ? edst[e] : e - NE;
    float ex = __expf(logits[e] - m[d]);
    logits[e] = ex;
    atomicAdd(&den[d], ex);
}

// ---- pass C: acc[dst] += (ex/den[dst]) * xl[src] ----
__global__ void k_edge_scatter(const int* __restrict__ esrc, const int* __restrict__ edst,
                               const float* __restrict__ xl, const float* __restrict__ ex,
                               const float* __restrict__ den, float* __restrict__ acc) {
    int lane = threadIdx.x & 63;
    int e = blockIdx.x * 4 + (threadIdx.x >> 6);
    if (e >= ET) return;
    int s, d;
    if (e < NE) { s = esrc[e]; d = edst[e]; }
    else        { s = d = e - NE; }
    float alpha = ex[e] / den[d];
    atomicAdd(&acc[(size_t)d * HID + lane], alpha * xl[(size_t)s * HID + lane]);
}

// ---- mean-pool: run-length aware (batch is sorted) ----
__global__ void k_pool(const float* __restrict__ acc, const int* __restrict__ batch,
                       float* __restrict__ pooled) {
    const int CH = 32;
    int c = threadIdx.x & 63;
    int j = threadIdx.x >> 6;
    int base = blockIdx.x * (4 * CH) + j * CH;
    float sum = 0.f;
    int g = -1;
    for (int t = 0; t < CH; t++) {
        int n = base + t;
        if (n >= NN) break;
        int bg = batch[n];
        if (bg != g) {
            if (g >= 0) atomicAdd(&pooled[(size_t)g * HID + c], sum);
            g = bg;
            sum = 0.f;
        }
        sum += acc[(size_t)n * HID + c];
    }
    if (g >= 0) atomicAdd(&pooled[(size_t)g * HID + c], sum);
}

__global__ void k_cnt(const int* __restrict__ batch, float* __restrict__ cnt) {
    int i = blockIdx.x * 256 + threadIdx.x;
    if (i < NN) atomicAdd(&cnt[batch[i]], 1.f);
}

// ---- head: out[g] = (pooled[g]/cnt[g]) . Wf + bf ----
__global__ void k_final(const float* __restrict__ pooled, const float* __restrict__ cnt,
                        const float* __restrict__ Wf, const float* __restrict__ bf_,
                        float* __restrict__ out) {
    int g = blockIdx.x;
    int c = threadIdx.x;
    float v = pooled[(size_t)g * HID + c] / fmaxf(cnt[g], 1.f) * Wf[c];
#pragma unroll
    for (int o = 32; o; o >>= 1) v += __shfl_xor(v, o, 64);
    if (c == 0) out[g] = v + bf_[0];
}

extern "C" void kernel_launch(void* const* d_in, const int* in_sizes, int n_in,
                              void* d_out, int out_size, void* d_ws, size_t ws_size,
                              hipStream_t stream) {
    const float* x   = (const float*)d_in[0];
    const int* eidx  = (const int*)d_in[1];
    const int* batch = (const int*)d_in[2];
    const int* esrc = eidx;
    const int* edst = eidx + NE;
    const float* Wf  = (const float*)d_in[21];
    const float* bfb = (const float*)d_in[22];

    // ws layout (floats)
    float* wsf = (float*)d_ws;
    const size_t NN64 = (size_t)NN * HID;
    float* xl     = wsf;
    float* xr     = xl + NN64;
    float* acc0   = xr + NN64;
    float* acc1   = acc0 + NN64;
    float* m      = acc1 + NN64;
    float* den    = m + NN;
    float* logits = den + NN;
    float* pooled = logits + ET;
    float* cnt    = pooled + (size_t)NG * HID;

    k_init_pool<<<(NG * HID + 255) / 256, 256, 0, stream>>>(pooled, cnt);

    float* accs[4] = {acc0, acc0, acc1, acc0};  // out of layer L = accs[L+1]
    for (int L = 0; L < 3; L++) {
        const float* Wl  = (const float*)d_in[3 + L * 6 + 0];
        const float* Wr  = (const float*)d_in[3 + L * 6 + 1];
        const float* att = (const float*)d_in[3 + L * 6 + 2];
        const float* b   = (const float*)d_in[3 + L * 6 + 3];
        const float* Rw  = (const float*)d_in[3 + L * 6 + 4];
        const float* Rb  = (const float*)d_in[3 + L * 6 + 5];
        float* accOut = accs[L + 1];

        k_init_md<<<(NN + 255) / 256, 256, 0, stream>>>(m, den);

        if (L == 0)
            k_gemm<DIN0, false><<<(NN + 3) / 4, 256, 0, stream>>>(
                x, Wl, Wr, Rw, b, Rb, xl, xr, accOut);
        else
            k_gemm<HID, true><<<(NN + 3) / 4, 256, 0, stream>>>(
                accs[L], Wl, Wr, Rw, b, Rb, xl, xr, accOut);

        k_edge_logits<<<(ET + 3) / 4, 256, 0, stream>>>(esrc, edst, xl, xr, att, logits, m);
        k_edge_exp<<<(ET + 255) / 256, 256, 0, stream>>>(edst, m, logits, den);
        k_edge_scatter<<<(ET + 3) / 4, 256, 0, stream>>>(esrc, edst, xl, logits, den, accOut);
    }

    k_pool<<<(NN + 127) / 128, 256, 0, stream>>>(accs[3], batch, pooled);
    k_cnt<<<(NN + 255) / 256, 256, 0, stream>>>(batch, cnt);
    k_final<<<NG, HID, 0, stream>>>(pooled, cnt, Wf, bfb, (float*)d_out);
}

// Round 3
// 1759.322 us; speedup vs baseline: 1.5204x; 1.5204x over previous
//
#include <hip/hip_runtime.h>

// GATv2 3-layer + mean-pool + linear head, MI355X.
// All float tensors f32; ints int32. Output f32. Intermediates in f32 workspace.

#define NN 50000
#define NE 1000000
#define ET (NE + NN)          // edges + self loops
#define HID 64
#define DIN0 128
#define NG 256
#define NEG 0.2f

// float atomic max via int/uint monotonic bit trick (m init to -inf)
__device__ __forceinline__ void atomicMaxF(float* addr, float val) {
    if (val >= 0.f) atomicMax((int*)addr, __float_as_int(val));
    else            atomicMin((unsigned*)addr, (unsigned)__float_as_int(val));
}

__global__ void k_init_md(float* __restrict__ m, float* __restrict__ den) {
    int i = blockIdx.x * 256 + threadIdx.x;
    if (i < NN) { m[i] = -INFINITY; den[i] = 0.f; }
}

__global__ void k_init_pool(float* __restrict__ pooled, float* __restrict__ cnt) {
    int i = blockIdx.x * 256 + threadIdx.x;
    if (i < NG * HID) pooled[i] = 0.f;
    if (i < NG) cnt[i] = 0.f;
}

// ---- fused node GEMMs: xl = x@Wl^T, xr = x@Wr^T, acc = x@Rw^T + Rb + b ----
// LDS-tiled: block = 64 nodes x 192 outputs, K chunks of 64.
// LDS: x-tile [64n][64k] (k XOR-swizzled by node) + W tiles [3][64k][64c]
// (c XOR-swizzled by k, k-major so one ds_read_b128 = 4 channels).
// Thread (cg,ng): 4 channels x 4 nodes micro-tile; per k: 3 b128 + 4 b32 -> 48 FMA.
template <int DIN, bool RELU>
__global__ __launch_bounds__(256) void k_gemm(
        const float* __restrict__ xin,
        const float* __restrict__ Wl, const float* __restrict__ Wr,
        const float* __restrict__ Rw,
        const float* __restrict__ bvec, const float* __restrict__ rb,
        float* __restrict__ xl, float* __restrict__ xr, float* __restrict__ acc) {
    constexpr int KC = 64;
    __shared__ float xs[64 * KC];       // 16 KB
    __shared__ float ws[3 * KC * 64];   // 48 KB

    const int tid = threadIdx.x;
    const int cg = tid & 15;            // channels 4cg..4cg+3
    const int ng = tid >> 4;            // nodes 4ng..4ng+3
    const int nb0 = blockIdx.x * 64;

    float4 al[4], ar[4], av[4];
#pragma unroll
    for (int i = 0; i < 4; i++) {
        al[i] = make_float4(0.f, 0.f, 0.f, 0.f);
        ar[i] = make_float4(0.f, 0.f, 0.f, 0.f);
        av[i] = make_float4(0.f, 0.f, 0.f, 0.f);
    }

    for (int c0 = 0; c0 < DIN; c0 += KC) {
        if (c0) __syncthreads();
        // stage x tile (coalesced float4, swizzled LDS write)
        for (int idx = tid; idx < 64 * (KC / 4); idx += 256) {
            int row = idx >> 4, kq = idx & 15;
            int n = nb0 + row;
            float4 v = make_float4(0.f, 0.f, 0.f, 0.f);
            if (n < NN) {
                v = *(const float4*)&xin[(size_t)n * DIN + c0 + 4 * kq];
                if (RELU) {
                    v.x = fmaxf(v.x, 0.f); v.y = fmaxf(v.y, 0.f);
                    v.z = fmaxf(v.z, 0.f); v.w = fmaxf(v.w, 0.f);
                }
            }
            *(float4*)&xs[row * KC + 4 * (kq ^ (row & 7))] = v;
        }
        // stage W tiles transposed to [m][k][c], c XOR-swizzled by k
        for (int idx = tid; idx < 3 * 64 * (KC / 4); idx += 256) {
            int mm = idx >> 10;
            int r = idx & 1023;
            int crow = r >> 4, kq = r & 15;
            const float* Wm = (mm == 0) ? Wl : (mm == 1) ? Wr : Rw;
            float4 v = *(const float4*)&Wm[(size_t)crow * DIN + c0 + 4 * kq];
            int k0 = 4 * kq;
#pragma unroll
            for (int j = 0; j < 4; j++) {
                int k = k0 + j;
                ws[(mm * KC + k) * 64 + (crow ^ ((k & 15) << 2))] = (&v.x)[j];
            }
        }
        __syncthreads();

        const int xk0 = ((4 * ng + 0) & 7) << 2;
        const int xk1 = ((4 * ng + 1) & 7) << 2;
        const int xk2 = ((4 * ng + 2) & 7) << 2;
        const int xk3 = ((4 * ng + 3) & 7) << 2;
#pragma unroll 8
        for (int k = 0; k < KC; k++) {
            int g = 4 * (cg ^ (k & 15));
            float4 w0 = *(const float4*)&ws[(0 * KC + k) * 64 + g];
            float4 w1 = *(const float4*)&ws[(1 * KC + k) * 64 + g];
            float4 w2 = *(const float4*)&ws[(2 * KC + k) * 64 + g];
            float xv[4];
            xv[0] = xs[(4 * ng + 0) * KC + (k ^ xk0)];
            xv[1] = xs[(4 * ng + 1) * KC + (k ^ xk1)];
            xv[2] = xs[(4 * ng + 2) * KC + (k ^ xk2)];
            xv[3] = xs[(4 * ng + 3) * KC + (k ^ xk3)];
#pragma unroll
            for (int i = 0; i < 4; i++) {
                float xi = xv[i];
                al[i].x += xi * w0.x; al[i].y += xi * w0.y; al[i].z += xi * w0.z; al[i].w += xi * w0.w;
                ar[i].x += xi * w1.x; ar[i].y += xi * w1.y; ar[i].z += xi * w1.z; ar[i].w += xi * w1.w;
                av[i].x += xi * w2.x; av[i].y += xi * w2.y; av[i].z += xi * w2.z; av[i].w += xi * w2.w;
            }
        }
    }

    float4 b4 = ((const float4*)bvec)[cg];
    float4 r4 = ((const float4*)rb)[cg];
#pragma unroll
    for (int i = 0; i < 4; i++) {
        int n = nb0 + 4 * ng + i;
        if (n < NN) {
            ((float4*)&xl[(size_t)n * HID])[cg] = al[i];
            ((float4*)&xr[(size_t)n * HID])[cg] = ar[i];
            float4 o = av[i];
            o.x += b4.x + r4.x; o.y += b4.y + r4.y;
            o.z += b4.z + r4.z; o.w += b4.w + r4.w;
            ((float4*)&acc[(size_t)n * HID])[cg] = o;
        }
    }
}

// ---- pass A: logits[e] = leaky(xl[src]+xr[dst]) . att ; m[dst] = max ----
__global__ void k_edge_logits(const int* __restrict__ esrc, const int* __restrict__ edst,
                              const float* __restrict__ xl, const float* __restrict__ xr,
                              const float* __restrict__ att,
                              float* __restrict__ logits, float* __restrict__ m) {
    int lane = threadIdx.x & 63;
    int e = blockIdx.x * 4 + (threadIdx.x >> 6);
    if (e >= ET) return;
    int s, d;
    if (e < NE) { s = esrc[e]; d = edst[e]; }
    else        { s = d = e - NE; }
    float v = xl[(size_t)s * HID + lane] + xr[(size_t)d * HID + lane];
    v = (v > 0.f) ? v : NEG * v;
    float t = v * att[lane];
#pragma unroll
    for (int o = 32; o; o >>= 1) t += __shfl_xor(t, o, 64);
    if (lane == 0) {
        logits[e] = t;
        atomicMaxF(&m[d], t);
    }
}

// ---- pass B: ex = exp(logit - m[dst]); den[dst] += ex ----
__global__ void k_edge_exp(const int* __restrict__ edst, const float* __restrict__ m,
                           float* __restrict__ logits, float* __restrict__ den) {
    int e = blockIdx.x * 256 + threadIdx.x;
    if (e >= ET) return;
    int d = (e < NE) ? edst[e] : e - NE;
    float ex = __expf(logits[e] - m[d]);
    logits[e] = ex;
    atomicAdd(&den[d], ex);
}

// ---- pass C: acc[dst] += (ex/den[dst]) * xl[src] ----
__global__ void k_edge_scatter(const int* __restrict__ esrc, const int* __restrict__ edst,
                               const float* __restrict__ xl, const float* __restrict__ ex,
                               const float* __restrict__ den, float* __restrict__ acc) {
    int lane = threadIdx.x & 63;
    int e = blockIdx.x * 4 + (threadIdx.x >> 6);
    if (e >= ET) return;
    int s, d;
    if (e < NE) { s = esrc[e]; d = edst[e]; }
    else        { s = d = e - NE; }
    float alpha = ex[e] / den[d];
    atomicAdd(&acc[(size_t)d * HID + lane], alpha * xl[(size_t)s * HID + lane]);
}

// ---- mean-pool: run-length aware (batch is sorted) ----
__global__ void k_pool(const float* __restrict__ acc, const int* __restrict__ batch,
                       float* __restrict__ pooled) {
    const int CH = 32;
    int c = threadIdx.x & 63;
    int j = threadIdx.x >> 6;
    int base = blockIdx.x * (4 * CH) + j * CH;
    float sum = 0.f;
    int g = -1;
    for (int t = 0; t < CH; t++) {
        int n = base + t;
        if (n >= NN) break;
        int bg = batch[n];
        if (bg != g) {
            if (g >= 0) atomicAdd(&pooled[(size_t)g * HID + c], sum);
            g = bg;
            sum = 0.f;
        }
        sum += acc[(size_t)n * HID + c];
    }
    if (g >= 0) atomicAdd(&pooled[(size_t)g * HID + c], sum);
}

__global__ void k_cnt(const int* __restrict__ batch, float* __restrict__ cnt) {
    int i = blockIdx.x * 256 + threadIdx.x;
    if (i < NN) atomicAdd(&cnt[batch[i]], 1.f);
}

// ---- head: out[g] = (pooled[g]/cnt[g]) . Wf + bf ----
__global__ void k_final(const float* __restrict__ pooled, const float* __restrict__ cnt,
                        const float* __restrict__ Wf, const float* __restrict__ bf_,
                        float* __restrict__ out) {
    int g = blockIdx.x;
    int c = threadIdx.x;
    float v = pooled[(size_t)g * HID + c] / fmaxf(cnt[g], 1.f) * Wf[c];
#pragma unroll
    for (int o = 32; o; o >>= 1) v += __shfl_xor(v, o, 64);
    if (c == 0) out[g] = v + bf_[0];
}

extern "C" void kernel_launch(void* const* d_in, const int* in_sizes, int n_in,
                              void* d_out, int out_size, void* d_ws, size_t ws_size,
                              hipStream_t stream) {
    const float* x   = (const float*)d_in[0];
    const int* eidx  = (const int*)d_in[1];
    const int* batch = (const int*)d_in[2];
    const int* esrc = eidx;
    const int* edst = eidx + NE;
    const float* Wf  = (const float*)d_in[21];
    const float* bfb = (const float*)d_in[22];

    float* wsf = (float*)d_ws;
    const size_t NN64 = (size_t)NN * HID;
    float* xl     = wsf;
    float* xr     = xl + NN64;
    float* acc0   = xr + NN64;
    float* acc1   = acc0 + NN64;
    float* m      = acc1 + NN64;
    float* den    = m + NN;
    float* logits = den + NN;
    float* pooled = logits + ET;
    float* cnt    = pooled + (size_t)NG * HID;

    k_init_pool<<<(NG * HID + 255) / 256, 256, 0, stream>>>(pooled, cnt);

    float* accs[4] = {acc0, acc0, acc1, acc0};  // out of layer L = accs[L+1]
    const int gemm_grid = (NN + 63) / 64;
    for (int L = 0; L < 3; L++) {
        const float* Wl  = (const float*)d_in[3 + L * 6 + 0];
        const float* Wr  = (const float*)d_in[3 + L * 6 + 1];
        const float* att = (const float*)d_in[3 + L * 6 + 2];
        const float* b   = (const float*)d_in[3 + L * 6 + 3];
        const float* Rw  = (const float*)d_in[3 + L * 6 + 4];
        const float* Rb  = (const float*)d_in[3 + L * 6 + 5];
        float* accOut = accs[L + 1];

        k_init_md<<<(NN + 255) / 256, 256, 0, stream>>>(m, den);

        if (L == 0)
            k_gemm<DIN0, false><<<gemm_grid, 256, 0, stream>>>(
                x, Wl, Wr, Rw, b, Rb, xl, xr, accOut);
        else
            k_gemm<HID, true><<<gemm_grid, 256, 0, stream>>>(
                accs[L], Wl, Wr, Rw, b, Rb, xl, xr, accOut);

        k_edge_logits<<<(ET + 3) / 4, 256, 0, stream>>>(esrc, edst, xl, xr, att, logits, m);
        k_edge_exp<<<(ET + 255) / 256, 256, 0, stream>>>(edst, m, logits, den);
        k_edge_scatter<<<(ET + 3) / 4, 256, 0, stream>>>(esrc, edst, xl, logits, den, accOut);
    }

    k_pool<<<(NN + 127) / 128, 256, 0, stream>>>(accs[3], batch, pooled);
    k_cnt<<<(NN + 255) / 256, 256, 0, stream>>>(batch, cnt);
    k_final<<<NG, HID, 0, stream>>>(pooled, cnt, Wf, bfb, (float*)d_out);
}

// Round 5
// 874.367 us; speedup vs baseline: 3.0592x; 2.0121x over previous
//
#include <hip/hip_runtime.h>

// GATv2 3-layer + mean-pool + linear head, MI355X.
// R4: dst-CSR built once; fused per-dst online-softmax attention (no atomics,
// single xl gather). Self-loop handled as explicit init (R3's folded-index
// version was UB -> NaN). All float tensors f32; ints int32.

#define NN 50000
#define NE 1000000
#define HID 64
#define DIN0 128
#define NG 256
#define NEG 0.2f

__global__ void k_init_pool(float* __restrict__ pooled, float* __restrict__ cnt) {
    int i = blockIdx.x * 256 + threadIdx.x;
    if (i < NG * HID) pooled[i] = 0.f;
    if (i < NG) cnt[i] = 0.f;
}

// ---- CSR build ----
__global__ void k_zero_int(int* __restrict__ p, int n) {
    int i = blockIdx.x * 256 + threadIdx.x;
    if (i < n) p[i] = 0;
}

__global__ void k_hist(const int* __restrict__ edst, int* __restrict__ cnt) {
    int e = blockIdx.x * 256 + threadIdx.x;
    if (e < NE) atomicAdd(&cnt[edst[e]], 1);
}

// single-block exclusive scan over NN counters -> off[NN+1], cursor copy
__global__ __launch_bounds__(1024) void k_scan(const int* __restrict__ cnt,
                                               int* __restrict__ off,
                                               int* __restrict__ cursor) {
    __shared__ int part[1024];
    const int t = threadIdx.x;
    const int CH = (NN + 1023) / 1024;
    int lo = t * CH, hi = min(lo + CH, NN);
    int s = 0;
    for (int i = lo; i < hi; i++) s += cnt[i];
    part[t] = s;
    __syncthreads();
    for (int d = 1; d < 1024; d <<= 1) {
        int v = (t >= d) ? part[t - d] : 0;
        __syncthreads();
        part[t] += v;
        __syncthreads();
    }
    int base = (t == 0) ? 0 : part[t - 1];
    for (int i = lo; i < hi; i++) {
        off[i] = base; cursor[i] = base; base += cnt[i];
    }
    if (t == 1023) off[NN] = base;
}

__global__ void k_scatter_ids(const int* __restrict__ esrc, const int* __restrict__ edst,
                              int* __restrict__ cursor, int* __restrict__ srcs) {
    int e = blockIdx.x * 256 + threadIdx.x;
    if (e >= NE) return;
    int pos = atomicAdd(&cursor[edst[e]], 1);
    srcs[pos] = esrc[e];
}

// ---- fused node GEMMs: xl = x@Wl^T, xr = x@Wr^T, acc = x@Rw^T + Rb + b ----
template <int DIN, bool RELU>
__global__ __launch_bounds__(256) void k_gemm(
        const float* __restrict__ xin,
        const float* __restrict__ Wl, const float* __restrict__ Wr,
        const float* __restrict__ Rw,
        const float* __restrict__ bvec, const float* __restrict__ rb,
        float* __restrict__ xl, float* __restrict__ xr, float* __restrict__ acc) {
    constexpr int KC = 64;
    __shared__ float xs[64 * KC];       // 16 KB
    __shared__ float ws[3 * KC * 64];   // 48 KB

    const int tid = threadIdx.x;
    const int cg = tid & 15;            // channels 4cg..4cg+3
    const int ng = tid >> 4;            // nodes 4ng..4ng+3
    const int nb0 = blockIdx.x * 64;

    float4 al[4], ar[4], av[4];
#pragma unroll
    for (int i = 0; i < 4; i++) {
        al[i] = make_float4(0.f, 0.f, 0.f, 0.f);
        ar[i] = make_float4(0.f, 0.f, 0.f, 0.f);
        av[i] = make_float4(0.f, 0.f, 0.f, 0.f);
    }

    for (int c0 = 0; c0 < DIN; c0 += KC) {
        if (c0) __syncthreads();
        for (int idx = tid; idx < 64 * (KC / 4); idx += 256) {
            int row = idx >> 4, kq = idx & 15;
            int n = nb0 + row;
            float4 v = make_float4(0.f, 0.f, 0.f, 0.f);
            if (n < NN) {
                v = *(const float4*)&xin[(size_t)n * DIN + c0 + 4 * kq];
                if (RELU) {
                    v.x = fmaxf(v.x, 0.f); v.y = fmaxf(v.y, 0.f);
                    v.z = fmaxf(v.z, 0.f); v.w = fmaxf(v.w, 0.f);
                }
            }
            *(float4*)&xs[row * KC + 4 * (kq ^ (row & 7))] = v;
        }
        for (int idx = tid; idx < 3 * 64 * (KC / 4); idx += 256) {
            int mm = idx >> 10;
            int r = idx & 1023;
            int crow = r >> 4, kq = r & 15;
            const float* Wm = (mm == 0) ? Wl : (mm == 1) ? Wr : Rw;
            float4 v = *(const float4*)&Wm[(size_t)crow * DIN + c0 + 4 * kq];
            int k0 = 4 * kq;
#pragma unroll
            for (int j = 0; j < 4; j++) {
                int k = k0 + j;
                ws[(mm * KC + k) * 64 + (crow ^ ((k & 15) << 2))] = (&v.x)[j];
            }
        }
        __syncthreads();

        const int xk0 = ((4 * ng + 0) & 7) << 2;
        const int xk1 = ((4 * ng + 1) & 7) << 2;
        const int xk2 = ((4 * ng + 2) & 7) << 2;
        const int xk3 = ((4 * ng + 3) & 7) << 2;
#pragma unroll 8
        for (int k = 0; k < KC; k++) {
            int g = 4 * (cg ^ (k & 15));
            float4 w0 = *(const float4*)&ws[(0 * KC + k) * 64 + g];
            float4 w1 = *(const float4*)&ws[(1 * KC + k) * 64 + g];
            float4 w2 = *(const float4*)&ws[(2 * KC + k) * 64 + g];
            float xv[4];
            xv[0] = xs[(4 * ng + 0) * KC + (k ^ xk0)];
            xv[1] = xs[(4 * ng + 1) * KC + (k ^ xk1)];
            xv[2] = xs[(4 * ng + 2) * KC + (k ^ xk2)];
            xv[3] = xs[(4 * ng + 3) * KC + (k ^ xk3)];
#pragma unroll
            for (int i = 0; i < 4; i++) {
                float xi = xv[i];
                al[i].x += xi * w0.x; al[i].y += xi * w0.y; al[i].z += xi * w0.z; al[i].w += xi * w0.w;
                ar[i].x += xi * w1.x; ar[i].y += xi * w1.y; ar[i].z += xi * w1.z; ar[i].w += xi * w1.w;
                av[i].x += xi * w2.x; av[i].y += xi * w2.y; av[i].z += xi * w2.z; av[i].w += xi * w2.w;
            }
        }
    }

    float4 b4 = ((const float4*)bvec)[cg];
    float4 r4 = ((const float4*)rb)[cg];
#pragma unroll
    for (int i = 0; i < 4; i++) {
        int n = nb0 + 4 * ng + i;
        if (n < NN) {
            ((float4*)&xl[(size_t)n * HID])[cg] = al[i];
            ((float4*)&xr[(size_t)n * HID])[cg] = ar[i];
            float4 o = av[i];
            o.x += b4.x + r4.x; o.y += b4.y + r4.y;
            o.z += b4.z + r4.z; o.w += b4.w + r4.w;
            ((float4*)&acc[(size_t)n * HID])[cg] = o;
        }
    }
}

// ---- fused per-dst attention: online softmax over self loop + incoming edges.
// wave per dst, lane = channel. acc[dst] += sum_e alpha_e * xl[src_e].
__global__ __launch_bounds__(256) void k_attn_dst(
        const int* __restrict__ off, const int* __restrict__ srcs,
        const float* __restrict__ xl, const float* __restrict__ xr,
        const float* __restrict__ att, float* __restrict__ acc) {
    const int lane = threadIdx.x & 63;
    const int d = blockIdx.x * 4 + (threadIdx.x >> 6);
    if (d >= NN) return;

    const float attv = att[lane];
    const float xrv = xr[(size_t)d * HID + lane];

    // self loop: init state (alpha contribution exp(0)=1 at m = t_self)
    float m, l, o;
    {
        float xlv = xl[(size_t)d * HID + lane];
        float v = xlv + xrv;
        v = (v > 0.f) ? v : NEG * v;
        float t = v * attv;
#pragma unroll
        for (int w = 32; w; w >>= 1) t += __shfl_xor(t, w, 64);
        m = t; l = 1.f; o = xlv;
    }

    const int lo = off[d], deg = off[d + 1] - lo;
    for (int base = 0; base < deg; base += 64) {
        int nv = min(64, deg - base);
        int sv = 0;
        if (base + lane < deg) sv = srcs[lo + base + lane];
        for (int j = 0; j < nv; j++) {
            int s = __shfl(sv, j, 64);
            float xlv = xl[(size_t)s * HID + lane];
            float v = xlv + xrv;
            v = (v > 0.f) ? v : NEG * v;
            float t = v * attv;
#pragma unroll
            for (int w = 32; w; w >>= 1) t += __shfl_xor(t, w, 64);
            float newm = fmaxf(m, t);
            float corr = __expf(m - newm);
            float p = __expf(t - newm);
            l = l * corr + p;
            o = o * corr + p * xlv;
            m = newm;
        }
    }

    size_t idx = (size_t)d * HID + lane;
    acc[idx] += o / l;
}

// ---- mean-pool: run-length aware (batch is sorted) ----
__global__ void k_pool(const float* __restrict__ acc, const int* __restrict__ batch,
                       float* __restrict__ pooled) {
    const int CH = 32;
    int c = threadIdx.x & 63;
    int j = threadIdx.x >> 6;
    int base = blockIdx.x * (4 * CH) + j * CH;
    float sum = 0.f;
    int g = -1;
    for (int t = 0; t < CH; t++) {
        int n = base + t;
        if (n >= NN) break;
        int bg = batch[n];
        if (bg != g) {
            if (g >= 0) atomicAdd(&pooled[(size_t)g * HID + c], sum);
            g = bg;
            sum = 0.f;
        }
        sum += acc[(size_t)n * HID + c];
    }
    if (g >= 0) atomicAdd(&pooled[(size_t)g * HID + c], sum);
}

__global__ void k_cnt(const int* __restrict__ batch, float* __restrict__ cnt) {
    int i = blockIdx.x * 256 + threadIdx.x;
    if (i < NN) atomicAdd(&cnt[batch[i]], 1.f);
}

__global__ void k_final(const float* __restrict__ pooled, const float* __restrict__ cnt,
                        const float* __restrict__ Wf, const float* __restrict__ bf_,
                        float* __restrict__ out) {
    int g = blockIdx.x;
    int c = threadIdx.x;
    float v = pooled[(size_t)g * HID + c] / fmaxf(cnt[g], 1.f) * Wf[c];
#pragma unroll
    for (int o = 32; o; o >>= 1) v += __shfl_xor(v, o, 64);
    if (c == 0) out[g] = v + bf_[0];
}

extern "C" void kernel_launch(void* const* d_in, const int* in_sizes, int n_in,
                              void* d_out, int out_size, void* d_ws, size_t ws_size,
                              hipStream_t stream) {
    const float* x   = (const float*)d_in[0];
    const int* eidx  = (const int*)d_in[1];
    const int* batch = (const int*)d_in[2];
    const int* esrc = eidx;
    const int* edst = eidx + NE;
    const float* Wf  = (const float*)d_in[21];
    const float* bfb = (const float*)d_in[22];

    float* wsf = (float*)d_ws;
    const size_t NN64 = (size_t)NN * HID;
    float* xl     = wsf;
    float* xr     = xl + NN64;
    float* acc0   = xr + NN64;
    float* acc1   = acc0 + NN64;
    float* pooled = acc1 + NN64;
    float* cnt    = pooled + (size_t)NG * HID;
    int*   ccnt   = (int*)(cnt + NG);
    int*   off    = ccnt + NN;
    int*   cursor = off + NN + 1;
    int*   srcs   = cursor + NN;

    // CSR build (once; reused by all 3 layers)
    k_zero_int<<<(NN + 255) / 256, 256, 0, stream>>>(ccnt, NN);
    k_hist<<<(NE + 255) / 256, 256, 0, stream>>>(edst, ccnt);
    k_scan<<<1, 1024, 0, stream>>>(ccnt, off, cursor);
    k_scatter_ids<<<(NE + 255) / 256, 256, 0, stream>>>(esrc, edst, cursor, srcs);

    k_init_pool<<<(NG * HID + 255) / 256, 256, 0, stream>>>(pooled, cnt);

    float* accs[4] = {acc0, acc0, acc1, acc0};  // out of layer L = accs[L+1]
    const int gemm_grid = (NN + 63) / 64;
    for (int L = 0; L < 3; L++) {
        const float* Wl  = (const float*)d_in[3 + L * 6 + 0];
        const float* Wr  = (const float*)d_in[3 + L * 6 + 1];
        const float* att = (const float*)d_in[3 + L * 6 + 2];
        const float* b   = (const float*)d_in[3 + L * 6 + 3];
        const float* Rw  = (const float*)d_in[3 + L * 6 + 4];
        const float* Rb  = (const float*)d_in[3 + L * 6 + 5];
        float* accOut = accs[L + 1];

        if (L == 0)
            k_gemm<DIN0, false><<<gemm_grid, 256, 0, stream>>>(
                x, Wl, Wr, Rw, b, Rb, xl, xr, accOut);
        else
            k_gemm<HID, true><<<gemm_grid, 256, 0, stream>>>(
                accs[L], Wl, Wr, Rw, b, Rb, xl, xr, accOut);

        k_attn_dst<<<(NN + 3) / 4, 256, 0, stream>>>(off, srcs, xl, xr, att, accOut);
    }

    k_pool<<<(NN + 127) / 128, 256, 0, stream>>>(accs[3], batch, pooled);
    k_cnt<<<(NN + 255) / 256, 256, 0, stream>>>(batch, cnt);
    k_final<<<NG, HID, 0, stream>>>(pooled, cnt, Wf, bfb, (float*)d_out);
}

// Round 6
// 775.136 us; speedup vs baseline: 3.4509x; 1.1280x over previous
//
#include <hip/hip_runtime.h>

// GATv2 3-layer + mean-pool + linear head, MI355X.
// R5: multi-block CSR scan (R4's single-block k_scan was 112 us / 13% of total).
// dst-CSR built once; fused per-dst online-softmax attention (no atomics).

#define NN 50000
#define NE 1000000
#define HID 64
#define DIN0 128
#define NG 256
#define NEG 0.2f

#define SCHUNK 1024
#define SNB ((NN + SCHUNK - 1) / SCHUNK)   // 49 blocks

__global__ void k_init_pool(float* __restrict__ pooled, float* __restrict__ cnt) {
    int i = blockIdx.x * 256 + threadIdx.x;
    if (i < NG * HID) pooled[i] = 0.f;
    if (i < NG) cnt[i] = 0.f;
}

// ---- CSR build ----
__global__ void k_zero_int(int* __restrict__ p, int n) {
    int i = blockIdx.x * 256 + threadIdx.x;
    if (i < n) p[i] = 0;
}

__global__ void k_hist(const int* __restrict__ edst, int* __restrict__ cnt) {
    int e = blockIdx.x * 256 + threadIdx.x;
    if (e < NE) atomicAdd(&cnt[edst[e]], 1);
}

// phase A: per-block chunk sums
__global__ __launch_bounds__(256) void k_scan_part(const int* __restrict__ cnt,
                                                   int* __restrict__ part) {
    __shared__ int ws[4];
    int b = blockIdx.x, t = threadIdx.x;
    int i0 = b * SCHUNK + t * 4;
    int s = 0;
#pragma unroll
    for (int j = 0; j < 4; j++) {
        int i = i0 + j;
        if (i < NN) s += cnt[i];
    }
#pragma unroll
    for (int o = 32; o; o >>= 1) s += __shfl_xor(s, o, 64);
    if ((t & 63) == 0) ws[t >> 6] = s;
    __syncthreads();
    if (t == 0) part[b] = ws[0] + ws[1] + ws[2] + ws[3];
}

// phase B: exclusive scan of SNB partials (one tiny block)
__global__ void k_scan_small(const int* __restrict__ part, int* __restrict__ partScan) {
    __shared__ int sh[SNB];
    int t = threadIdx.x;
    if (t < SNB) sh[t] = part[t];
    __syncthreads();
    if (t < SNB) {
        int s = 0;
        for (int i = 0; i < t; i++) s += sh[i];
        partScan[t] = s;
    }
}

// phase C: in-block exclusive scan + base, emit off/cursor (+ off[NN])
__global__ __launch_bounds__(256) void k_scan_emit(const int* __restrict__ cnt,
                                                   const int* __restrict__ partScan,
                                                   int* __restrict__ off,
                                                   int* __restrict__ cursor) {
    __shared__ int tsum[256];
    int b = blockIdx.x, t = threadIdx.x;
    int i0 = b * SCHUNK + t * 4;
    int e[4], p[4];
    int s = 0;
#pragma unroll
    for (int j = 0; j < 4; j++) {
        int i = i0 + j;
        e[j] = (i < NN) ? cnt[i] : 0;
        p[j] = s;          // local exclusive prefix
        s += e[j];
    }
    tsum[t] = s;
    __syncthreads();
    // Hillis-Steele inclusive scan over 256 thread sums
    for (int d = 1; d < 256; d <<= 1) {
        int v = (t >= d) ? tsum[t - d] : 0;
        __syncthreads();
        tsum[t] += v;
        __syncthreads();
    }
    int base = partScan[b] + ((t == 0) ? 0 : tsum[t - 1]);
#pragma unroll
    for (int j = 0; j < 4; j++) {
        int i = i0 + j;
        if (i < NN) {
            int v = base + p[j];
            off[i] = v; cursor[i] = v;
            if (i == NN - 1) off[NN] = v + e[j];
        }
    }
}

__global__ void k_scatter_ids(const int* __restrict__ esrc, const int* __restrict__ edst,
                              int* __restrict__ cursor, int* __restrict__ srcs) {
    int e = blockIdx.x * 256 + threadIdx.x;
    if (e >= NE) return;
    int pos = atomicAdd(&cursor[edst[e]], 1);
    srcs[pos] = esrc[e];
}

// ---- fused node GEMMs: xl = x@Wl^T, xr = x@Wr^T, acc = x@Rw^T + Rb + b ----
template <int DIN, bool RELU>
__global__ __launch_bounds__(256) void k_gemm(
        const float* __restrict__ xin,
        const float* __restrict__ Wl, const float* __restrict__ Wr,
        const float* __restrict__ Rw,
        const float* __restrict__ bvec, const float* __restrict__ rb,
        float* __restrict__ xl, float* __restrict__ xr, float* __restrict__ acc) {
    constexpr int KC = 64;
    __shared__ float xs[64 * KC];       // 16 KB
    __shared__ float ws[3 * KC * 64];   // 48 KB

    const int tid = threadIdx.x;
    const int cg = tid & 15;            // channels 4cg..4cg+3
    const int ng = tid >> 4;            // nodes 4ng..4ng+3
    const int nb0 = blockIdx.x * 64;

    float4 al[4], ar[4], av[4];
#pragma unroll
    for (int i = 0; i < 4; i++) {
        al[i] = make_float4(0.f, 0.f, 0.f, 0.f);
        ar[i] = make_float4(0.f, 0.f, 0.f, 0.f);
        av[i] = make_float4(0.f, 0.f, 0.f, 0.f);
    }

    for (int c0 = 0; c0 < DIN; c0 += KC) {
        if (c0) __syncthreads();
        for (int idx = tid; idx < 64 * (KC / 4); idx += 256) {
            int row = idx >> 4, kq = idx & 15;
            int n = nb0 + row;
            float4 v = make_float4(0.f, 0.f, 0.f, 0.f);
            if (n < NN) {
                v = *(const float4*)&xin[(size_t)n * DIN + c0 + 4 * kq];
                if (RELU) {
                    v.x = fmaxf(v.x, 0.f); v.y = fmaxf(v.y, 0.f);
                    v.z = fmaxf(v.z, 0.f); v.w = fmaxf(v.w, 0.f);
                }
            }
            *(float4*)&xs[row * KC + 4 * (kq ^ (row & 7))] = v;
        }
        for (int idx = tid; idx < 3 * 64 * (KC / 4); idx += 256) {
            int mm = idx >> 10;
            int r = idx & 1023;
            int crow = r >> 4, kq = r & 15;
            const float* Wm = (mm == 0) ? Wl : (mm == 1) ? Wr : Rw;
            float4 v = *(const float4*)&Wm[(size_t)crow * DIN + c0 + 4 * kq];
            int k0 = 4 * kq;
#pragma unroll
            for (int j = 0; j < 4; j++) {
                int k = k0 + j;
                ws[(mm * KC + k) * 64 + (crow ^ ((k & 15) << 2))] = (&v.x)[j];
            }
        }
        __syncthreads();

        const int xk0 = ((4 * ng + 0) & 7) << 2;
        const int xk1 = ((4 * ng + 1) & 7) << 2;
        const int xk2 = ((4 * ng + 2) & 7) << 2;
        const int xk3 = ((4 * ng + 3) & 7) << 2;
#pragma unroll 8
        for (int k = 0; k < KC; k++) {
            int g = 4 * (cg ^ (k & 15));
            float4 w0 = *(const float4*)&ws[(0 * KC + k) * 64 + g];
            float4 w1 = *(const float4*)&ws[(1 * KC + k) * 64 + g];
            float4 w2 = *(const float4*)&ws[(2 * KC + k) * 64 + g];
            float xv[4];
            xv[0] = xs[(4 * ng + 0) * KC + (k ^ xk0)];
            xv[1] = xs[(4 * ng + 1) * KC + (k ^ xk1)];
            xv[2] = xs[(4 * ng + 2) * KC + (k ^ xk2)];
            xv[3] = xs[(4 * ng + 3) * KC + (k ^ xk3)];
#pragma unroll
            for (int i = 0; i < 4; i++) {
                float xi = xv[i];
                al[i].x += xi * w0.x; al[i].y += xi * w0.y; al[i].z += xi * w0.z; al[i].w += xi * w0.w;
                ar[i].x += xi * w1.x; ar[i].y += xi * w1.y; ar[i].z += xi * w1.z; ar[i].w += xi * w1.w;
                av[i].x += xi * w2.x; av[i].y += xi * w2.y; av[i].z += xi * w2.z; av[i].w += xi * w2.w;
            }
        }
    }

    float4 b4 = ((const float4*)bvec)[cg];
    float4 r4 = ((const float4*)rb)[cg];
#pragma unroll
    for (int i = 0; i < 4; i++) {
        int n = nb0 + 4 * ng + i;
        if (n < NN) {
            ((float4*)&xl[(size_t)n * HID])[cg] = al[i];
            ((float4*)&xr[(size_t)n * HID])[cg] = ar[i];
            float4 o = av[i];
            o.x += b4.x + r4.x; o.y += b4.y + r4.y;
            o.z += b4.z + r4.z; o.w += b4.w + r4.w;
            ((float4*)&acc[(size_t)n * HID])[cg] = o;
        }
    }
}

// ---- fused per-dst attention: online softmax over self loop + incoming edges.
__global__ __launch_bounds__(256) void k_attn_dst(
        const int* __restrict__ off, const int* __restrict__ srcs,
        const float* __restrict__ xl, const float* __restrict__ xr,
        const float* __restrict__ att, float* __restrict__ acc) {
    const int lane = threadIdx.x & 63;
    const int d = blockIdx.x * 4 + (threadIdx.x >> 6);
    if (d >= NN) return;

    const float attv = att[lane];
    const float xrv = xr[(size_t)d * HID + lane];

    // self loop: init state
    float m, l, o;
    {
        float xlv = xl[(size_t)d * HID + lane];
        float v = xlv + xrv;
        v = (v > 0.f) ? v : NEG * v;
        float t = v * attv;
#pragma unroll
        for (int w = 32; w; w >>= 1) t += __shfl_xor(t, w, 64);
        m = t; l = 1.f; o = xlv;
    }

    const int lo = off[d], deg = off[d + 1] - lo;
    for (int base = 0; base < deg; base += 64) {
        int nv = min(64, deg - base);
        int sv = 0;
        if (base + lane < deg) sv = srcs[lo + base + lane];
        for (int j = 0; j < nv; j++) {
            int s = __shfl(sv, j, 64);
            float xlv = xl[(size_t)s * HID + lane];
            float v = xlv + xrv;
            v = (v > 0.f) ? v : NEG * v;
            float t = v * attv;
#pragma unroll
            for (int w = 32; w; w >>= 1) t += __shfl_xor(t, w, 64);
            float newm = fmaxf(m, t);
            float corr = __expf(m - newm);
            float p = __expf(t - newm);
            l = l * corr + p;
            o = o * corr + p * xlv;
            m = newm;
        }
    }

    size_t idx = (size_t)d * HID + lane;
    acc[idx] += o / l;
}

// ---- mean-pool: run-length aware (batch is sorted) ----
__global__ void k_pool(const float* __restrict__ acc, const int* __restrict__ batch,
                       float* __restrict__ pooled) {
    const int CH = 32;
    int c = threadIdx.x & 63;
    int j = threadIdx.x >> 6;
    int base = blockIdx.x * (4 * CH) + j * CH;
    float sum = 0.f;
    int g = -1;
    for (int t = 0; t < CH; t++) {
        int n = base + t;
        if (n >= NN) break;
        int bg = batch[n];
        if (bg != g) {
            if (g >= 0) atomicAdd(&pooled[(size_t)g * HID + c], sum);
            g = bg;
            sum = 0.f;
        }
        sum += acc[(size_t)n * HID + c];
    }
    if (g >= 0) atomicAdd(&pooled[(size_t)g * HID + c], sum);
}

__global__ void k_cnt(const int* __restrict__ batch, float* __restrict__ cnt) {
    int i = blockIdx.x * 256 + threadIdx.x;
    if (i < NN) atomicAdd(&cnt[batch[i]], 1.f);
}

__global__ void k_final(const float* __restrict__ pooled, const float* __restrict__ cnt,
                        const float* __restrict__ Wf, const float* __restrict__ bf_,
                        float* __restrict__ out) {
    int g = blockIdx.x;
    int c = threadIdx.x;
    float v = pooled[(size_t)g * HID + c] / fmaxf(cnt[g], 1.f) * Wf[c];
#pragma unroll
    for (int o = 32; o; o >>= 1) v += __shfl_xor(v, o, 64);
    if (c == 0) out[g] = v + bf_[0];
}

extern "C" void kernel_launch(void* const* d_in, const int* in_sizes, int n_in,
                              void* d_out, int out_size, void* d_ws, size_t ws_size,
                              hipStream_t stream) {
    const float* x   = (const float*)d_in[0];
    const int* eidx  = (const int*)d_in[1];
    const int* batch = (const int*)d_in[2];
    const int* esrc = eidx;
    const int* edst = eidx + NE;
    const float* Wf  = (const float*)d_in[21];
    const float* bfb = (const float*)d_in[22];

    float* wsf = (float*)d_ws;
    const size_t NN64 = (size_t)NN * HID;
    float* xl     = wsf;
    float* xr     = xl + NN64;
    float* acc0   = xr + NN64;
    float* acc1   = acc0 + NN64;
    float* pooled = acc1 + NN64;
    float* cnt    = pooled + (size_t)NG * HID;
    int*   ccnt   = (int*)(cnt + NG);
    int*   off    = ccnt + NN;
    int*   cursor = off + NN + 1;
    int*   part   = cursor + NN;
    int*   partSc = part + SNB;
    int*   srcs   = partSc + SNB;

    // CSR build (once; reused by all 3 layers)
    k_zero_int<<<(NN + 255) / 256, 256, 0, stream>>>(ccnt, NN);
    k_hist<<<(NE + 255) / 256, 256, 0, stream>>>(edst, ccnt);
    k_scan_part<<<SNB, 256, 0, stream>>>(ccnt, part);
    k_scan_small<<<1, 64, 0, stream>>>(part, partSc);
    k_scan_emit<<<SNB, 256, 0, stream>>>(ccnt, partSc, off, cursor);
    k_scatter_ids<<<(NE + 255) / 256, 256, 0, stream>>>(esrc, edst, cursor, srcs);

    k_init_pool<<<(NG * HID + 255) / 256, 256, 0, stream>>>(pooled, cnt);

    float* accs[4] = {acc0, acc0, acc1, acc0};  // out of layer L = accs[L+1]
    const int gemm_grid = (NN + 63) / 64;
    for (int L = 0; L < 3; L++) {
        const float* Wl  = (const float*)d_in[3 + L * 6 + 0];
        const float* Wr  = (const float*)d_in[3 + L * 6 + 1];
        const float* att = (const float*)d_in[3 + L * 6 + 2];
        const float* b   = (const float*)d_in[3 + L * 6 + 3];
        const float* Rw  = (const float*)d_in[3 + L * 6 + 4];
        const float* Rb  = (const float*)d_in[3 + L * 6 + 5];
        float* accOut = accs[L + 1];

        if (L == 0)
            k_gemm<DIN0, false><<<gemm_grid, 256, 0, stream>>>(
                x, Wl, Wr, Rw, b, Rb, xl, xr, accOut);
        else
            k_gemm<HID, true><<<gemm_grid, 256, 0, stream>>>(
                accs[L], Wl, Wr, Rw, b, Rb, xl, xr, accOut);

        k_attn_dst<<<(NN + 3) / 4, 256, 0, stream>>>(off, srcs, xl, xr, att, accOut);
    }

    k_pool<<<(NN + 127) / 128, 256, 0, stream>>>(accs[3], batch, pooled);
    k_cnt<<<(NN + 255) / 256, 256, 0, stream>>>(batch, cnt);
    k_final<<<NG, HID, 0, stream>>>(pooled, cnt, Wf, bfb, (float*)d_out);
}

// Round 7
// 596.965 us; speedup vs baseline: 4.4808x; 1.2985x over previous
//
#include <hip/hip_runtime.h>

// GATv2 3-layer + mean-pool + linear head, MI355X.
// R6: k_attn_dst restructured as 8-edges x 8-channels per wave with
// chunk-level online softmax (was: 1 edge/wave-iter with 6-shuffle butterfly
// + per-edge serial exp chain -> 110us each; 51% VALUBusy).

#define NN 50000
#define NE 1000000
#define HID 64
#define DIN0 128
#define NG 256
#define NEG 0.2f

#define SCHUNK 1024
#define SNB ((NN + SCHUNK - 1) / SCHUNK)   // 49 blocks

__global__ void k_init_pool(float* __restrict__ pooled, float* __restrict__ cnt) {
    int i = blockIdx.x * 256 + threadIdx.x;
    if (i < NG * HID) pooled[i] = 0.f;
    if (i < NG) cnt[i] = 0.f;
}

// ---- CSR build ----
__global__ void k_zero_int(int* __restrict__ p, int n) {
    int i = blockIdx.x * 256 + threadIdx.x;
    if (i < n) p[i] = 0;
}

__global__ void k_hist(const int* __restrict__ edst, int* __restrict__ cnt) {
    int e = blockIdx.x * 256 + threadIdx.x;
    if (e < NE) atomicAdd(&cnt[edst[e]], 1);
}

__global__ __launch_bounds__(256) void k_scan_part(const int* __restrict__ cnt,
                                                   int* __restrict__ part) {
    __shared__ int ws[4];
    int b = blockIdx.x, t = threadIdx.x;
    int i0 = b * SCHUNK + t * 4;
    int s = 0;
#pragma unroll
    for (int j = 0; j < 4; j++) {
        int i = i0 + j;
        if (i < NN) s += cnt[i];
    }
#pragma unroll
    for (int o = 32; o; o >>= 1) s += __shfl_xor(s, o, 64);
    if ((t & 63) == 0) ws[t >> 6] = s;
    __syncthreads();
    if (t == 0) part[b] = ws[0] + ws[1] + ws[2] + ws[3];
}

__global__ void k_scan_small(const int* __restrict__ part, int* __restrict__ partScan) {
    __shared__ int sh[SNB];
    int t = threadIdx.x;
    if (t < SNB) sh[t] = part[t];
    __syncthreads();
    if (t < SNB) {
        int s = 0;
        for (int i = 0; i < t; i++) s += sh[i];
        partScan[t] = s;
    }
}

__global__ __launch_bounds__(256) void k_scan_emit(const int* __restrict__ cnt,
                                                   const int* __restrict__ partScan,
                                                   int* __restrict__ off,
                                                   int* __restrict__ cursor) {
    __shared__ int tsum[256];
    int b = blockIdx.x, t = threadIdx.x;
    int i0 = b * SCHUNK + t * 4;
    int e[4], p[4];
    int s = 0;
#pragma unroll
    for (int j = 0; j < 4; j++) {
        int i = i0 + j;
        e[j] = (i < NN) ? cnt[i] : 0;
        p[j] = s;
        s += e[j];
    }
    tsum[t] = s;
    __syncthreads();
    for (int d = 1; d < 256; d <<= 1) {
        int v = (t >= d) ? tsum[t - d] : 0;
        __syncthreads();
        tsum[t] += v;
        __syncthreads();
    }
    int base = partScan[b] + ((t == 0) ? 0 : tsum[t - 1]);
#pragma unroll
    for (int j = 0; j < 4; j++) {
        int i = i0 + j;
        if (i < NN) {
            int v = base + p[j];
            off[i] = v; cursor[i] = v;
            if (i == NN - 1) off[NN] = v + e[j];
        }
    }
}

__global__ void k_scatter_ids(const int* __restrict__ esrc, const int* __restrict__ edst,
                              int* __restrict__ cursor, int* __restrict__ srcs) {
    int e = blockIdx.x * 256 + threadIdx.x;
    if (e >= NE) return;
    int pos = atomicAdd(&cursor[edst[e]], 1);
    srcs[pos] = esrc[e];
}

// ---- fused node GEMMs: xl = x@Wl^T, xr = x@Wr^T, acc = x@Rw^T + Rb + b ----
template <int DIN, bool RELU>
__global__ __launch_bounds__(256) void k_gemm(
        const float* __restrict__ xin,
        const float* __restrict__ Wl, const float* __restrict__ Wr,
        const float* __restrict__ Rw,
        const float* __restrict__ bvec, const float* __restrict__ rb,
        float* __restrict__ xl, float* __restrict__ xr, float* __restrict__ acc) {
    constexpr int KC = 64;
    __shared__ float xs[64 * KC];       // 16 KB
    __shared__ float ws[3 * KC * 64];   // 48 KB

    const int tid = threadIdx.x;
    const int cg = tid & 15;
    const int ng = tid >> 4;
    const int nb0 = blockIdx.x * 64;

    float4 al[4], ar[4], av[4];
#pragma unroll
    for (int i = 0; i < 4; i++) {
        al[i] = make_float4(0.f, 0.f, 0.f, 0.f);
        ar[i] = make_float4(0.f, 0.f, 0.f, 0.f);
        av[i] = make_float4(0.f, 0.f, 0.f, 0.f);
    }

    for (int c0 = 0; c0 < DIN; c0 += KC) {
        if (c0) __syncthreads();
        for (int idx = tid; idx < 64 * (KC / 4); idx += 256) {
            int row = idx >> 4, kq = idx & 15;
            int n = nb0 + row;
            float4 v = make_float4(0.f, 0.f, 0.f, 0.f);
            if (n < NN) {
                v = *(const float4*)&xin[(size_t)n * DIN + c0 + 4 * kq];
                if (RELU) {
                    v.x = fmaxf(v.x, 0.f); v.y = fmaxf(v.y, 0.f);
                    v.z = fmaxf(v.z, 0.f); v.w = fmaxf(v.w, 0.f);
                }
            }
            *(float4*)&xs[row * KC + 4 * (kq ^ (row & 7))] = v;
        }
        for (int idx = tid; idx < 3 * 64 * (KC / 4); idx += 256) {
            int mm = idx >> 10;
            int r = idx & 1023;
            int crow = r >> 4, kq = r & 15;
            const float* Wm = (mm == 0) ? Wl : (mm == 1) ? Wr : Rw;
            float4 v = *(const float4*)&Wm[(size_t)crow * DIN + c0 + 4 * kq];
            int k0 = 4 * kq;
#pragma unroll
            for (int j = 0; j < 4; j++) {
                int k = k0 + j;
                ws[(mm * KC + k) * 64 + (crow ^ ((k & 15) << 2))] = (&v.x)[j];
            }
        }
        __syncthreads();

        const int xk0 = ((4 * ng + 0) & 7) << 2;
        const int xk1 = ((4 * ng + 1) & 7) << 2;
        const int xk2 = ((4 * ng + 2) & 7) << 2;
        const int xk3 = ((4 * ng + 3) & 7) << 2;
#pragma unroll 8
        for (int k = 0; k < KC; k++) {
            int g = 4 * (cg ^ (k & 15));
            float4 w0 = *(const float4*)&ws[(0 * KC + k) * 64 + g];
            float4 w1 = *(const float4*)&ws[(1 * KC + k) * 64 + g];
            float4 w2 = *(const float4*)&ws[(2 * KC + k) * 64 + g];
            float xv[4];
            xv[0] = xs[(4 * ng + 0) * KC + (k ^ xk0)];
            xv[1] = xs[(4 * ng + 1) * KC + (k ^ xk1)];
            xv[2] = xs[(4 * ng + 2) * KC + (k ^ xk2)];
            xv[3] = xs[(4 * ng + 3) * KC + (k ^ xk3)];
#pragma unroll
            for (int i = 0; i < 4; i++) {
                float xi = xv[i];
                al[i].x += xi * w0.x; al[i].y += xi * w0.y; al[i].z += xi * w0.z; al[i].w += xi * w0.w;
                ar[i].x += xi * w1.x; ar[i].y += xi * w1.y; ar[i].z += xi * w1.z; ar[i].w += xi * w1.w;
                av[i].x += xi * w2.x; av[i].y += xi * w2.y; av[i].z += xi * w2.z; av[i].w += xi * w2.w;
            }
        }
    }

    float4 b4 = ((const float4*)bvec)[cg];
    float4 r4 = ((const float4*)rb)[cg];
#pragma unroll
    for (int i = 0; i < 4; i++) {
        int n = nb0 + 4 * ng + i;
        if (n < NN) {
            ((float4*)&xl[(size_t)n * HID])[cg] = al[i];
            ((float4*)&xr[(size_t)n * HID])[cg] = ar[i];
            float4 o = av[i];
            o.x += b4.x + r4.x; o.y += b4.y + r4.y;
            o.z += b4.z + r4.z; o.w += b4.w + r4.w;
            ((float4*)&acc[(size_t)n * HID])[cg] = o;
        }
    }
}

// ---- fused per-dst attention: 8 edges x 8 channels per wave ----
// lane = e*8 + cg; lane covers channels 8cg..8cg+7 of edge-slot e.
// Chunk-level online softmax: one max-corr per 8 edges.
__global__ __launch_bounds__(256) void k_attn_dst(
        const int* __restrict__ off, const int* __restrict__ srcs,
        const float* __restrict__ xl, const float* __restrict__ xr,
        const float* __restrict__ att, float* __restrict__ acc) {
    const int lane = threadIdx.x & 63;
    const int d = blockIdx.x * 4 + (threadIdx.x >> 6);
    if (d >= NN) return;
    const int e = lane >> 3;
    const int cg = lane & 7;

    const float4* xr4 = (const float4*)&xr[(size_t)d * HID + 8 * cg];
    float4 xra = xr4[0], xrb = xr4[1];
    const float4* at4 = (const float4*)&att[8 * cg];
    float4 ata = at4[0], atb = at4[1];

#define EDGE_LOGIT(S, XA, XB, T)                                               \
    {                                                                          \
        const float4* _x4 = (const float4*)&xl[(size_t)(S) * HID + 8 * cg];    \
        XA = _x4[0]; XB = _x4[1];                                              \
        float _ps;                                                             \
        float _v;                                                              \
        _v = XA.x + xra.x; _ps  = (fmaxf(_v,0.f) + NEG*fminf(_v,0.f)) * ata.x; \
        _v = XA.y + xra.y; _ps += (fmaxf(_v,0.f) + NEG*fminf(_v,0.f)) * ata.y; \
        _v = XA.z + xra.z; _ps += (fmaxf(_v,0.f) + NEG*fminf(_v,0.f)) * ata.z; \
        _v = XA.w + xra.w; _ps += (fmaxf(_v,0.f) + NEG*fminf(_v,0.f)) * ata.w; \
        _v = XB.x + xrb.x; _ps += (fmaxf(_v,0.f) + NEG*fminf(_v,0.f)) * atb.x; \
        _v = XB.y + xrb.y; _ps += (fmaxf(_v,0.f) + NEG*fminf(_v,0.f)) * atb.y; \
        _v = XB.z + xrb.z; _ps += (fmaxf(_v,0.f) + NEG*fminf(_v,0.f)) * atb.z; \
        _v = XB.w + xrb.w; _ps += (fmaxf(_v,0.f) + NEG*fminf(_v,0.f)) * atb.w; \
        _ps += __shfl_xor(_ps, 1, 64);                                         \
        _ps += __shfl_xor(_ps, 2, 64);                                         \
        _ps += __shfl_xor(_ps, 4, 64);                                         \
        T = _ps;                                                               \
    }

    // self loop prologue (s = d); p_self = 1, counted only in e-slot 0
    float m, l;
    float4 oA, oB;
    {
        float4 xla, xlb; float t;
        EDGE_LOGIT(d, xla, xlb, t);
        m = t;
        bool own = (e == 0);
        l = own ? 1.f : 0.f;
        oA = own ? xla : make_float4(0.f, 0.f, 0.f, 0.f);
        oB = own ? xlb : make_float4(0.f, 0.f, 0.f, 0.f);
    }

    const int lo = off[d], deg = off[d + 1] - lo;
    for (int base = 0; base < deg; base += 8) {
        int nv = deg - base;                // >=1
        int sv = 0;
        if (lane < 8) sv = srcs[lo + min(base + lane, deg - 1)];
        int s = __shfl(sv, e, 64);

        float4 xla, xlb; float t;
        EDGE_LOGIT(s, xla, xlb, t);
        if (e >= nv) t = -INFINITY;

        // chunk max over e-groups
        float cm = t;
        cm = fmaxf(cm, __shfl_xor(cm, 8, 64));
        cm = fmaxf(cm, __shfl_xor(cm, 16, 64));
        cm = fmaxf(cm, __shfl_xor(cm, 32, 64));
        float newm = fmaxf(m, cm);
        float corr = __expf(m - newm);
        float p = __expf(t - newm);         // -inf -> 0
        m = newm;
        l = l * corr + p;
        oA.x = oA.x * corr + p * xla.x; oA.y = oA.y * corr + p * xla.y;
        oA.z = oA.z * corr + p * xla.z; oA.w = oA.w * corr + p * xla.w;
        oB.x = oB.x * corr + p * xlb.x; oB.y = oB.y * corr + p * xlb.y;
        oB.z = oB.z * corr + p * xlb.z; oB.w = oB.w * corr + p * xlb.w;
    }
#undef EDGE_LOGIT

    // reduce l, oA, oB over e-bits (8,16,32)
#pragma unroll
    for (int w = 8; w <= 32; w <<= 1) {
        l    += __shfl_xor(l, w, 64);
        oA.x += __shfl_xor(oA.x, w, 64); oA.y += __shfl_xor(oA.y, w, 64);
        oA.z += __shfl_xor(oA.z, w, 64); oA.w += __shfl_xor(oA.w, w, 64);
        oB.x += __shfl_xor(oB.x, w, 64); oB.y += __shfl_xor(oB.y, w, 64);
        oB.z += __shfl_xor(oB.z, w, 64); oB.w += __shfl_xor(oB.w, w, 64);
    }

    if (e == 0) {
        float inv = 1.f / l;
        float4* a4 = (float4*)&acc[(size_t)d * HID + 8 * cg];
        float4 c0 = a4[0], c1 = a4[1];
        c0.x += oA.x * inv; c0.y += oA.y * inv;
        c0.z += oA.z * inv; c0.w += oA.w * inv;
        c1.x += oB.x * inv; c1.y += oB.y * inv;
        c1.z += oB.z * inv; c1.w += oB.w * inv;
        a4[0] = c0; a4[1] = c1;
    }
}

// ---- mean-pool: run-length aware (batch is sorted) ----
__global__ void k_pool(const float* __restrict__ acc, const int* __restrict__ batch,
                       float* __restrict__ pooled) {
    const int CH = 32;
    int c = threadIdx.x & 63;
    int j = threadIdx.x >> 6;
    int base = blockIdx.x * (4 * CH) + j * CH;
    float sum = 0.f;
    int g = -1;
    for (int t = 0; t < CH; t++) {
        int n = base + t;
        if (n >= NN) break;
        int bg = batch[n];
        if (bg != g) {
            if (g >= 0) atomicAdd(&pooled[(size_t)g * HID + c], sum);
            g = bg;
            sum = 0.f;
        }
        sum += acc[(size_t)n * HID + c];
    }
    if (g >= 0) atomicAdd(&pooled[(size_t)g * HID + c], sum);
}

__global__ void k_cnt(const int* __restrict__ batch, float* __restrict__ cnt) {
    int i = blockIdx.x * 256 + threadIdx.x;
    if (i < NN) atomicAdd(&cnt[batch[i]], 1.f);
}

__global__ void k_final(const float* __restrict__ pooled, const float* __restrict__ cnt,
                        const float* __restrict__ Wf, const float* __restrict__ bf_,
                        float* __restrict__ out) {
    int g = blockIdx.x;
    int c = threadIdx.x;
    float v = pooled[(size_t)g * HID + c] / fmaxf(cnt[g], 1.f) * Wf[c];
#pragma unroll
    for (int o = 32; o; o >>= 1) v += __shfl_xor(v, o, 64);
    if (c == 0) out[g] = v + bf_[0];
}

extern "C" void kernel_launch(void* const* d_in, const int* in_sizes, int n_in,
                              void* d_out, int out_size, void* d_ws, size_t ws_size,
                              hipStream_t stream) {
    const float* x   = (const float*)d_in[0];
    const int* eidx  = (const int*)d_in[1];
    const int* batch = (const int*)d_in[2];
    const int* esrc = eidx;
    const int* edst = eidx + NE;
    const float* Wf  = (const float*)d_in[21];
    const float* bfb = (const float*)d_in[22];

    float* wsf = (float*)d_ws;
    const size_t NN64 = (size_t)NN * HID;
    float* xl     = wsf;
    float* xr     = xl + NN64;
    float* acc0   = xr + NN64;
    float* acc1   = acc0 + NN64;
    float* pooled = acc1 + NN64;
    float* cnt    = pooled + (size_t)NG * HID;
    int*   ccnt   = (int*)(cnt + NG);
    int*   off    = ccnt + NN;
    int*   cursor = off + NN + 1;
    int*   part   = cursor + NN;
    int*   partSc = part + SNB;
    int*   srcs   = partSc + SNB;

    // CSR build (once; reused by all 3 layers)
    k_zero_int<<<(NN + 255) / 256, 256, 0, stream>>>(ccnt, NN);
    k_hist<<<(NE + 255) / 256, 256, 0, stream>>>(edst, ccnt);
    k_scan_part<<<SNB, 256, 0, stream>>>(ccnt, part);
    k_scan_small<<<1, 64, 0, stream>>>(part, partSc);
    k_scan_emit<<<SNB, 256, 0, stream>>>(ccnt, partSc, off, cursor);
    k_scatter_ids<<<(NE + 255) / 256, 256, 0, stream>>>(esrc, edst, cursor, srcs);

    k_init_pool<<<(NG * HID + 255) / 256, 256, 0, stream>>>(pooled, cnt);

    float* accs[4] = {acc0, acc0, acc1, acc0};  // out of layer L = accs[L+1]
    const int gemm_grid = (NN + 63) / 64;
    for (int L = 0; L < 3; L++) {
        const float* Wl  = (const float*)d_in[3 + L * 6 + 0];
        const float* Wr  = (const float*)d_in[3 + L * 6 + 1];
        const float* att = (const float*)d_in[3 + L * 6 + 2];
        const float* b   = (const float*)d_in[3 + L * 6 + 3];
        const float* Rw  = (const float*)d_in[3 + L * 6 + 4];
        const float* Rb  = (const float*)d_in[3 + L * 6 + 5];
        float* accOut = accs[L + 1];

        if (L == 0)
            k_gemm<DIN0, false><<<gemm_grid, 256, 0, stream>>>(
                x, Wl, Wr, Rw, b, Rb, xl, xr, accOut);
        else
            k_gemm<HID, true><<<gemm_grid, 256, 0, stream>>>(
                accs[L], Wl, Wr, Rw, b, Rb, xl, xr, accOut);

        k_attn_dst<<<(NN + 3) / 4, 256, 0, stream>>>(off, srcs, xl, xr, att, accOut);
    }

    k_pool<<<(NN + 127) / 128, 256, 0, stream>>>(accs[3], batch, pooled);
    k_cnt<<<(NN + 255) / 256, 256, 0, stream>>>(batch, cnt);
    k_final<<<NG, HID, 0, stream>>>(pooled, cnt, Wf, bfb, (float*)d_out);
}

// Round 8
// 504.613 us; speedup vs baseline: 5.3009x; 1.1830x over previous
//
#include <hip/hip_runtime.h>

// GATv2 3-layer + mean-pool + linear head, MI355X.
// R7: pooling subsystem rebuilt — batch is sorted, so per-graph bounds come
// from boundary detection (was: 50K atomicAdds onto 256 counters = 78us of
// pure contention) and pool+head fuse into one block-per-graph kernel.

#define NN 50000
#define NE 1000000
#define HID 64
#define DIN0 128
#define NG 256
#define NEG 0.2f

#define SCHUNK 1024
#define SNB ((NN + SCHUNK - 1) / SCHUNK)   // 49 blocks

// ---- CSR build ----
__global__ void k_zero_int(int* __restrict__ p, int n) {
    int i = blockIdx.x * 256 + threadIdx.x;
    if (i < n) p[i] = 0;
}

__global__ void k_hist(const int* __restrict__ edst, int* __restrict__ cnt) {
    int e = blockIdx.x * 256 + threadIdx.x;
    if (e < NE) atomicAdd(&cnt[edst[e]], 1);
}

__global__ __launch_bounds__(256) void k_scan_part(const int* __restrict__ cnt,
                                                   int* __restrict__ part) {
    __shared__ int ws[4];
    int b = blockIdx.x, t = threadIdx.x;
    int i0 = b * SCHUNK + t * 4;
    int s = 0;
#pragma unroll
    for (int j = 0; j < 4; j++) {
        int i = i0 + j;
        if (i < NN) s += cnt[i];
    }
#pragma unroll
    for (int o = 32; o; o >>= 1) s += __shfl_xor(s, o, 64);
    if ((t & 63) == 0) ws[t >> 6] = s;
    __syncthreads();
    if (t == 0) part[b] = ws[0] + ws[1] + ws[2] + ws[3];
}

__global__ void k_scan_small(const int* __restrict__ part, int* __restrict__ partScan) {
    __shared__ int sh[SNB];
    int t = threadIdx.x;
    if (t < SNB) sh[t] = part[t];
    __syncthreads();
    if (t < SNB) {
        int s = 0;
        for (int i = 0; i < t; i++) s += sh[i];
        partScan[t] = s;
    }
}

__global__ __launch_bounds__(256) void k_scan_emit(const int* __restrict__ cnt,
                                                   const int* __restrict__ partScan,
                                                   int* __restrict__ off,
                                                   int* __restrict__ cursor) {
    __shared__ int tsum[256];
    int b = blockIdx.x, t = threadIdx.x;
    int i0 = b * SCHUNK + t * 4;
    int e[4], p[4];
    int s = 0;
#pragma unroll
    for (int j = 0; j < 4; j++) {
        int i = i0 + j;
        e[j] = (i < NN) ? cnt[i] : 0;
        p[j] = s;
        s += e[j];
    }
    tsum[t] = s;
    __syncthreads();
    for (int d = 1; d < 256; d <<= 1) {
        int v = (t >= d) ? tsum[t - d] : 0;
        __syncthreads();
        tsum[t] += v;
        __syncthreads();
    }
    int base = partScan[b] + ((t == 0) ? 0 : tsum[t - 1]);
#pragma unroll
    for (int j = 0; j < 4; j++) {
        int i = i0 + j;
        if (i < NN) {
            int v = base + p[j];
            off[i] = v; cursor[i] = v;
            if (i == NN - 1) off[NN] = v + e[j];
        }
    }
}

__global__ void k_scatter_ids(const int* __restrict__ esrc, const int* __restrict__ edst,
                              int* __restrict__ cursor, int* __restrict__ srcs) {
    int e = blockIdx.x * 256 + threadIdx.x;
    if (e >= NE) return;
    int pos = atomicAdd(&cursor[edst[e]], 1);
    srcs[pos] = esrc[e];
}

// ---- per-graph node range from sorted batch (no atomics) ----
__global__ void k_bounds(const int* __restrict__ batch,
                         int* __restrict__ startg, int* __restrict__ endg) {
    int i = blockIdx.x * 256 + threadIdx.x;
    if (i >= NN) return;
    int g = batch[i];
    if (i == 0 || batch[i - 1] != g) startg[g] = i;
    if (i == NN - 1 || batch[i + 1] != g) endg[g] = i + 1;
}

// ---- fused node GEMMs: xl = x@Wl^T, xr = x@Wr^T, acc = x@Rw^T + Rb + b ----
template <int DIN, bool RELU>
__global__ __launch_bounds__(256) void k_gemm(
        const float* __restrict__ xin,
        const float* __restrict__ Wl, const float* __restrict__ Wr,
        const float* __restrict__ Rw,
        const float* __restrict__ bvec, const float* __restrict__ rb,
        float* __restrict__ xl, float* __restrict__ xr, float* __restrict__ acc) {
    constexpr int KC = 64;
    __shared__ float xs[64 * KC];       // 16 KB
    __shared__ float ws[3 * KC * 64];   // 48 KB

    const int tid = threadIdx.x;
    const int cg = tid & 15;
    const int ng = tid >> 4;
    const int nb0 = blockIdx.x * 64;

    float4 al[4], ar[4], av[4];
#pragma unroll
    for (int i = 0; i < 4; i++) {
        al[i] = make_float4(0.f, 0.f, 0.f, 0.f);
        ar[i] = make_float4(0.f, 0.f, 0.f, 0.f);
        av[i] = make_float4(0.f, 0.f, 0.f, 0.f);
    }

    for (int c0 = 0; c0 < DIN; c0 += KC) {
        if (c0) __syncthreads();
        for (int idx = tid; idx < 64 * (KC / 4); idx += 256) {
            int row = idx >> 4, kq = idx & 15;
            int n = nb0 + row;
            float4 v = make_float4(0.f, 0.f, 0.f, 0.f);
            if (n < NN) {
                v = *(const float4*)&xin[(size_t)n * DIN + c0 + 4 * kq];
                if (RELU) {
                    v.x = fmaxf(v.x, 0.f); v.y = fmaxf(v.y, 0.f);
                    v.z = fmaxf(v.z, 0.f); v.w = fmaxf(v.w, 0.f);
                }
            }
            *(float4*)&xs[row * KC + 4 * (kq ^ (row & 7))] = v;
        }
        for (int idx = tid; idx < 3 * 64 * (KC / 4); idx += 256) {
            int mm = idx >> 10;
            int r = idx & 1023;
            int crow = r >> 4, kq = r & 15;
            const float* Wm = (mm == 0) ? Wl : (mm == 1) ? Wr : Rw;
            float4 v = *(const float4*)&Wm[(size_t)crow * DIN + c0 + 4 * kq];
            int k0 = 4 * kq;
#pragma unroll
            for (int j = 0; j < 4; j++) {
                int k = k0 + j;
                ws[(mm * KC + k) * 64 + (crow ^ ((k & 15) << 2))] = (&v.x)[j];
            }
        }
        __syncthreads();

        const int xk0 = ((4 * ng + 0) & 7) << 2;
        const int xk1 = ((4 * ng + 1) & 7) << 2;
        const int xk2 = ((4 * ng + 2) & 7) << 2;
        const int xk3 = ((4 * ng + 3) & 7) << 2;
#pragma unroll 8
        for (int k = 0; k < KC; k++) {
            int g = 4 * (cg ^ (k & 15));
            float4 w0 = *(const float4*)&ws[(0 * KC + k) * 64 + g];
            float4 w1 = *(const float4*)&ws[(1 * KC + k) * 64 + g];
            float4 w2 = *(const float4*)&ws[(2 * KC + k) * 64 + g];
            float xv[4];
            xv[0] = xs[(4 * ng + 0) * KC + (k ^ xk0)];
            xv[1] = xs[(4 * ng + 1) * KC + (k ^ xk1)];
            xv[2] = xs[(4 * ng + 2) * KC + (k ^ xk2)];
            xv[3] = xs[(4 * ng + 3) * KC + (k ^ xk3)];
#pragma unroll
            for (int i = 0; i < 4; i++) {
                float xi = xv[i];
                al[i].x += xi * w0.x; al[i].y += xi * w0.y; al[i].z += xi * w0.z; al[i].w += xi * w0.w;
                ar[i].x += xi * w1.x; ar[i].y += xi * w1.y; ar[i].z += xi * w1.z; ar[i].w += xi * w1.w;
                av[i].x += xi * w2.x; av[i].y += xi * w2.y; av[i].z += xi * w2.z; av[i].w += xi * w2.w;
            }
        }
    }

    float4 b4 = ((const float4*)bvec)[cg];
    float4 r4 = ((const float4*)rb)[cg];
#pragma unroll
    for (int i = 0; i < 4; i++) {
        int n = nb0 + 4 * ng + i;
        if (n < NN) {
            ((float4*)&xl[(size_t)n * HID])[cg] = al[i];
            ((float4*)&xr[(size_t)n * HID])[cg] = ar[i];
            float4 o = av[i];
            o.x += b4.x + r4.x; o.y += b4.y + r4.y;
            o.z += b4.z + r4.z; o.w += b4.w + r4.w;
            ((float4*)&acc[(size_t)n * HID])[cg] = o;
        }
    }
}

// ---- fused per-dst attention: 8 edges x 8 channels per wave ----
__global__ __launch_bounds__(256) void k_attn_dst(
        const int* __restrict__ off, const int* __restrict__ srcs,
        const float* __restrict__ xl, const float* __restrict__ xr,
        const float* __restrict__ att, float* __restrict__ acc) {
    const int lane = threadIdx.x & 63;
    const int d = blockIdx.x * 4 + (threadIdx.x >> 6);
    if (d >= NN) return;
    const int e = lane >> 3;
    const int cg = lane & 7;

    const float4* xr4 = (const float4*)&xr[(size_t)d * HID + 8 * cg];
    float4 xra = xr4[0], xrb = xr4[1];
    const float4* at4 = (const float4*)&att[8 * cg];
    float4 ata = at4[0], atb = at4[1];

#define EDGE_LOGIT(S, XA, XB, T)                                               \
    {                                                                          \
        const float4* _x4 = (const float4*)&xl[(size_t)(S) * HID + 8 * cg];    \
        XA = _x4[0]; XB = _x4[1];                                              \
        float _ps;                                                             \
        float _v;                                                              \
        _v = XA.x + xra.x; _ps  = (fmaxf(_v,0.f) + NEG*fminf(_v,0.f)) * ata.x; \
        _v = XA.y + xra.y; _ps += (fmaxf(_v,0.f) + NEG*fminf(_v,0.f)) * ata.y; \
        _v = XA.z + xra.z; _ps += (fmaxf(_v,0.f) + NEG*fminf(_v,0.f)) * ata.z; \
        _v = XA.w + xra.w; _ps += (fmaxf(_v,0.f) + NEG*fminf(_v,0.f)) * ata.w; \
        _v = XB.x + xrb.x; _ps += (fmaxf(_v,0.f) + NEG*fminf(_v,0.f)) * atb.x; \
        _v = XB.y + xrb.y; _ps += (fmaxf(_v,0.f) + NEG*fminf(_v,0.f)) * atb.y; \
        _v = XB.z + xrb.z; _ps += (fmaxf(_v,0.f) + NEG*fminf(_v,0.f)) * atb.z; \
        _v = XB.w + xrb.w; _ps += (fmaxf(_v,0.f) + NEG*fminf(_v,0.f)) * atb.w; \
        _ps += __shfl_xor(_ps, 1, 64);                                         \
        _ps += __shfl_xor(_ps, 2, 64);                                         \
        _ps += __shfl_xor(_ps, 4, 64);                                         \
        T = _ps;                                                               \
    }

    float m, l;
    float4 oA, oB;
    {
        float4 xla, xlb; float t;
        EDGE_LOGIT(d, xla, xlb, t);
        m = t;
        bool own = (e == 0);
        l = own ? 1.f : 0.f;
        oA = own ? xla : make_float4(0.f, 0.f, 0.f, 0.f);
        oB = own ? xlb : make_float4(0.f, 0.f, 0.f, 0.f);
    }

    const int lo = off[d], deg = off[d + 1] - lo;
    for (int base = 0; base < deg; base += 8) {
        int nv = deg - base;
        int sv = 0;
        if (lane < 8) sv = srcs[lo + min(base + lane, deg - 1)];
        int s = __shfl(sv, e, 64);

        float4 xla, xlb; float t;
        EDGE_LOGIT(s, xla, xlb, t);
        if (e >= nv) t = -INFINITY;

        float cm = t;
        cm = fmaxf(cm, __shfl_xor(cm, 8, 64));
        cm = fmaxf(cm, __shfl_xor(cm, 16, 64));
        cm = fmaxf(cm, __shfl_xor(cm, 32, 64));
        float newm = fmaxf(m, cm);
        float corr = __expf(m - newm);
        float p = __expf(t - newm);
        m = newm;
        l = l * corr + p;
        oA.x = oA.x * corr + p * xla.x; oA.y = oA.y * corr + p * xla.y;
        oA.z = oA.z * corr + p * xla.z; oA.w = oA.w * corr + p * xla.w;
        oB.x = oB.x * corr + p * xlb.x; oB.y = oB.y * corr + p * xlb.y;
        oB.z = oB.z * corr + p * xlb.z; oB.w = oB.w * corr + p * xlb.w;
    }
#undef EDGE_LOGIT

#pragma unroll
    for (int w = 8; w <= 32; w <<= 1) {
        l    += __shfl_xor(l, w, 64);
        oA.x += __shfl_xor(oA.x, w, 64); oA.y += __shfl_xor(oA.y, w, 64);
        oA.z += __shfl_xor(oA.z, w, 64); oA.w += __shfl_xor(oA.w, w, 64);
        oB.x += __shfl_xor(oB.x, w, 64); oB.y += __shfl_xor(oB.y, w, 64);
        oB.z += __shfl_xor(oB.z, w, 64); oB.w += __shfl_xor(oB.w, w, 64);
    }

    if (e == 0) {
        float inv = 1.f / l;
        float4* a4 = (float4*)&acc[(size_t)d * HID + 8 * cg];
        float4 c0 = a4[0], c1 = a4[1];
        c0.x += oA.x * inv; c0.y += oA.y * inv;
        c0.z += oA.z * inv; c0.w += oA.w * inv;
        c1.x += oB.x * inv; c1.y += oB.y * inv;
        c1.z += oB.z * inv; c1.w += oB.w * inv;
        a4[0] = c0; a4[1] = c1;
    }
}

// ---- fused mean-pool + head: one block (512 thr) per graph ----
__global__ __launch_bounds__(512) void k_pool_final(
        const float* __restrict__ acc,
        const int* __restrict__ startg, const int* __restrict__ endg,
        const float* __restrict__ Wf, const float* __restrict__ bf_,
        float* __restrict__ out) {
    __shared__ float red[8][HID];
    const int g = blockIdx.x;
    const int c = threadIdx.x & 63;
    const int j = threadIdx.x >> 6;          // wave 0..7
    const int s = startg[g], epos = endg[g];

    float sum = 0.f;
    for (int n = s + j; n < epos; n += 8)
        sum += acc[(size_t)n * HID + c];
    red[j][c] = sum;
    __syncthreads();

    if (threadIdx.x < HID) {
        float tot = 0.f;
#pragma unroll
        for (int w = 0; w < 8; w++) tot += red[w][c];
        float cntf = (float)(epos - s);
        float v = tot / fmaxf(cntf, 1.f) * Wf[c];
#pragma unroll
        for (int o = 32; o; o >>= 1) v += __shfl_xor(v, o, 64);
        if (c == 0) out[g] = v + bf_[0];
    }
}

extern "C" void kernel_launch(void* const* d_in, const int* in_sizes, int n_in,
                              void* d_out, int out_size, void* d_ws, size_t ws_size,
                              hipStream_t stream) {
    const float* x   = (const float*)d_in[0];
    const int* eidx  = (const int*)d_in[1];
    const int* batch = (const int*)d_in[2];
    const int* esrc = eidx;
    const int* edst = eidx + NE;
    const float* Wf  = (const float*)d_in[21];
    const float* bfb = (const float*)d_in[22];

    float* wsf = (float*)d_ws;
    const size_t NN64 = (size_t)NN * HID;
    float* xl     = wsf;
    float* xr     = xl + NN64;
    float* acc0   = xr + NN64;
    float* acc1   = acc0 + NN64;
    int*   ccnt   = (int*)(acc1 + NN64);
    int*   startg = ccnt + NN;     // contiguous with ccnt for one zero-kernel
    int*   endg   = startg + NG;
    int*   off    = endg + NG;
    int*   cursor = off + NN + 1;
    int*   part   = cursor + NN;
    int*   partSc = part + SNB;
    int*   srcs   = partSc + SNB;

    // CSR build (once; reused by all 3 layers) + graph bounds
    k_zero_int<<<(NN + 2 * NG + 255) / 256, 256, 0, stream>>>(ccnt, NN + 2 * NG);
    k_hist<<<(NE + 255) / 256, 256, 0, stream>>>(edst, ccnt);
    k_scan_part<<<SNB, 256, 0, stream>>>(ccnt, part);
    k_scan_small<<<1, 64, 0, stream>>>(part, partSc);
    k_scan_emit<<<SNB, 256, 0, stream>>>(ccnt, partSc, off, cursor);
    k_scatter_ids<<<(NE + 255) / 256, 256, 0, stream>>>(esrc, edst, cursor, srcs);
    k_bounds<<<(NN + 255) / 256, 256, 0, stream>>>(batch, startg, endg);

    float* accs[4] = {acc0, acc0, acc1, acc0};  // out of layer L = accs[L+1]
    const int gemm_grid = (NN + 63) / 64;
    for (int L = 0; L < 3; L++) {
        const float* Wl  = (const float*)d_in[3 + L * 6 + 0];
        const float* Wr  = (const float*)d_in[3 + L * 6 + 1];
        const float* att = (const float*)d_in[3 + L * 6 + 2];
        const float* b   = (const float*)d_in[3 + L * 6 + 3];
        const float* Rw  = (const float*)d_in[3 + L * 6 + 4];
        const float* Rb  = (const float*)d_in[3 + L * 6 + 5];
        float* accOut = accs[L + 1];

        if (L == 0)
            k_gemm<DIN0, false><<<gemm_grid, 256, 0, stream>>>(
                x, Wl, Wr, Rw, b, Rb, xl, xr, accOut);
        else
            k_gemm<HID, true><<<gemm_grid, 256, 0, stream>>>(
                accs[L], Wl, Wr, Rw, b, Rb, xl, xr, accOut);

        k_attn_dst<<<(NN + 3) / 4, 256, 0, stream>>>(off, srcs, xl, xr, att, accOut);
    }

    k_pool_final<<<NG, 512, 0, stream>>>(accs[3], startg, endg, Wf, bfb, (float*)d_out);
}